// Round 1
// baseline (68.316 us; speedup 1.0000x reference)
//
#include <hip/hip_runtime.h>
#include <cstdint>

#define D 128
#define NEXP 9
#define TPB 256
#define CH 256            // tokens per chunk, all 9 experts (CH == TPB: single-pass compact)

typedef __bf16 bf16x8_t __attribute__((ext_vector_type(8)));
typedef float  f32x4_t  __attribute__((ext_vector_type(4)));

// Pack two fp32 into one uint32 of bf16 (round-to-nearest-even).
__device__ __forceinline__ uint32_t pack2_bf16(float a, float b) {
    uint32_t ua = __builtin_bit_cast(uint32_t, a);
    uint32_t ub = __builtin_bit_cast(uint32_t, b);
    ua += 0x7fffu + ((ua >> 16) & 1u);
    ub += 0x7fffu + ((ub >> 16) & 1u);
    return (ua >> 16) | (ub & 0xffff0000u);
}

__device__ __forceinline__ void async_copy16(const void* g, void* l) {
    __builtin_amdgcn_global_load_lds(
        (const __attribute__((address_space(1))) void*)g,
        (__attribute__((address_space(3))) void*)l,
        16, 0, 0);
}

// ---------------------------------------------------------------------------
// K1: one-shot prep. (a) W[9][128][128] fp32 -> WfG frag-order bf16 (the exact
// LDS image every main block will DMA), (b) x fp32 -> xb row-major bf16.
// Frag-order slot s: l=s&63, T=s>>6, q=l>>4, m=l&15, kt=T>>3, n=T&7;
// dword i of slot s = pack2( W[r][kt*32+q*8+2i][n*16+m], W[r][...+2i+1][...] ).
// Bit-identical to the previously verified in-block staging.
// ---------------------------------------------------------------------------
__global__ __launch_bounds__(TPB) void prep_kernel(
    const float* __restrict__ W, const float* __restrict__ x,
    uint32_t* __restrict__ WfG, uint32_t* __restrict__ xb,
    int nWitems, int nxitems)
{
    int gid = blockIdx.x * TPB + threadIdx.x;
    if (gid < nWitems) {
        int r = gid >> 11;          // 2048 slots per expert
        int s = gid & 2047;
        int l = s & 63, T = s >> 6;
        int q = l >> 4, m = l & 15;
        int kt = T >> 3, n = T & 7;
        const float* src = W + ((size_t)r << 14) + (kt * 32 + q * 8) * D + n * 16 + m;
        uint32_t u0 = pack2_bf16(src[0 * D], src[1 * D]);
        uint32_t u1 = pack2_bf16(src[2 * D], src[3 * D]);
        uint32_t u2 = pack2_bf16(src[4 * D], src[5 * D]);
        uint32_t u3 = pack2_bf16(src[6 * D], src[7 * D]);
        *reinterpret_cast<uint4*>(&WfG[(size_t)(r * 8192 + s * 4)]) = uint4{u0, u1, u2, u3};
    } else {
        int xi = gid - nWitems;     // item = 8 consecutive floats of x
        if (xi < nxitems) {
            const float4* src = reinterpret_cast<const float4*>(x + (size_t)xi * 8);
            float4 a = src[0], b = src[1];
            uint32_t u0 = pack2_bf16(a.x, a.y);
            uint32_t u1 = pack2_bf16(a.z, a.w);
            uint32_t u2 = pack2_bf16(b.x, b.y);
            uint32_t u3 = pack2_bf16(b.z, b.w);
            *reinterpret_cast<uint4*>(&xb[(size_t)xi * 4]) = uint4{u0, u1, u2, u3};
        }
    }
}

// ---------------------------------------------------------------------------
// K2: block = (expert r, 256-token chunk). Self-compacts its chunk, DMAs the
// precomputed 32 KB frag-order W image straight into LDS (global_load_lds,
// no VALU, no staging registers), then 16-token x 128-e MFMA tiles.
//
// Fragment layouts (gfx950, mfma_f32_16x16x32_bf16):
//   A: lane holds A[m=lane&15][k=(lane>>4)*8+j], j=0..7
//   B: lane holds B[k=(lane>>4)*8+j][n=lane&15]
//   D: lane,reg -> row m=(lane>>4)*4+reg, col n=lane&15   (m89-verified)
// ---------------------------------------------------------------------------
__global__ __launch_bounds__(TPB) void ltf_kernel(
    const int* __restrict__ pos, const uint32_t* __restrict__ WfG,
    const __bf16* __restrict__ xb, const float* __restrict__ bias,
    float* __restrict__ y, int ntok, int c0)
{
    __shared__ uint32_t Wf[8192];   // 32 KB frag-order W[r]
    __shared__ int lst[CH];
    __shared__ int cnt;

    const int tid  = threadIdx.x;
    const int lane = tid & 63;
    const int wv   = tid >> 6;
    const int bid  = blockIdx.x;

    const int r     = bid / c0;
    const int start = (bid - r * c0) * CH;
    const int end   = (start + CH < ntok) ? start + CH : ntok;

    // Issue pos load early; it resolves while the W DMA is being issued.
    const int t = start + tid;
    int pv = 0x7fffffff;
    if (t < end) pv = pos[t];

    if (tid == 0) cnt = 0;
    __syncthreads();

    // --- Stage W[r]: linear 32 KB DMA, 8 x 1 KB per wave. Wave-uniform LDS
    // base + lane*16 (global src per-lane) — exactly the frag-order image.
    {
        const uint32_t* wsrc = WfG + (size_t)r * 8192 + wv * 2048 + lane * 4;
        uint32_t* ldst = &Wf[wv * 2048];
        #pragma unroll
        for (int i = 0; i < 8; ++i)
            async_copy16(wsrc + i * 256, ldst + i * 256);
    }

    // --- Self-compact (single pass: CH == TPB), overlapped with the DMA.
    {
        int rp = pv < (NEXP - 1) ? pv : (NEXP - 1);
        bool m = (t < end) && (rp == r);
        unsigned long long mask = __ballot(m);
        int nm = __popcll(mask);
        int base = 0;
        if (lane == 0 && nm > 0) base = atomicAdd(&cnt, nm);
        base = __shfl(base, 0);
        if (m) lst[base + __popcll(mask & ((1ull << lane) - 1ull))] = t;
    }

    const int q = lane >> 4, mloc = lane & 15;

    // Per-lane bias for its 8 e-columns, issued before the barrier.
    float bvn[8];
    #pragma unroll
    for (int n = 0; n < 8; ++n) bvn[n] = bias[(size_t)r * D + n * 16 + mloc];

    __syncthreads();                 // drains DMA (vmcnt) + orders lst/cnt
    const int nc = cnt;

    for (int rd = 0; rd * 64 < nc; ++rd) {
        const int b16 = rd * 64 + wv * 16;   // this wave's 16-token group
        if (b16 >= nc) continue;

        int ta = b16 + mloc; if (ta >= nc) ta = nc - 1;  // dup tail (harmless)
        const int tokA = lst[ta];
        const __bf16* xrow = xb + (size_t)tokA * D;

        f32x4_t acc[8];
        #pragma unroll
        for (int n = 0; n < 8; ++n) acc[n] = f32x4_t{0.f, 0.f, 0.f, 0.f};

        #pragma unroll
        for (int kt = 0; kt < 4; ++kt) {
            // A-frag: 16 B bf16 load straight from precomputed xb.
            bf16x8_t av = *reinterpret_cast<const bf16x8_t*>(xrow + kt * 32 + q * 8);
            #pragma unroll
            for (int n = 0; n < 8; ++n) {
                bf16x8_t bf = *reinterpret_cast<const bf16x8_t*>(
                    &Wf[(kt * 8 + n) * 256 + lane * 4]);
                acc[n] = __builtin_amdgcn_mfma_f32_16x16x32_bf16(av, bf, acc[n], 0, 0, 0);
            }
        }

        // Epilogue: lane (q,reg) holds token row m = q*4+reg, col n*16+mloc.
        #pragma unroll
        for (int reg = 0; reg < 4; ++reg) {
            int tloc = b16 + q * 4 + reg;
            if (tloc < nc) {
                int tok = lst[tloc];
                float* yr = y + (size_t)tok * D + mloc;
                #pragma unroll
                for (int n = 0; n < 8; ++n)
                    yr[n * 16] = acc[n][reg] + bvn[n];
            }
        }
    }
}

extern "C" void kernel_launch(void* const* d_in, const int* in_sizes, int n_in,
                              void* d_out, int out_size, void* d_ws, size_t ws_size,
                              hipStream_t stream) {
    const int* pos  = (const int*)d_in[0];
    const float* x  = (const float*)d_in[1];
    const float* W  = (const float*)d_in[2];
    const float* b  = (const float*)d_in[3];
    float* y = (float*)d_out;

    const int ntok = in_sizes[0];            // T*B = 8192

    // Workspace layout: WfG (9*8192 dwords = 288 KB) at 0; xb at byte 512 KB.
    uint32_t* wsp = (uint32_t*)d_ws;
    uint32_t* WfG = wsp;
    uint32_t* xb  = wsp + 131072;

    const int nW = NEXP * 2048;              // frag slots total
    const int nx = ntok * 16;                // 8-float items of x
    const int gprep = (nW + nx + TPB - 1) / TPB;
    prep_kernel<<<gprep, TPB, 0, stream>>>(W, x, WfG, xb, nW, nx);

    const int c0 = (ntok + CH - 1) / CH;     // chunks per expert
    ltf_kernel<<<NEXP * c0, TPB, 0, stream>>>(pos, WfG, (const __bf16*)xb, b, y, ntok, c0);
}

// Round 2
// 66.850 us; speedup vs baseline: 1.0219x; 1.0219x over previous
//
#include <hip/hip_runtime.h>
#include <cstdint>

#define D 128
#define NEXP 9
#define TPB 256
#define CH0 512   // chunk size, experts 0..7 (expect ~43 matched)
#define CH8 128   // chunk size, overflow expert 8 (catches pos 8..11 = 4/12)

typedef __bf16 bf16x8_t __attribute__((ext_vector_type(8)));
typedef float  f32x4_t  __attribute__((ext_vector_type(4)));

union FragA { uint32_t u[4]; bf16x8_t v; };

// Pack two fp32 into one uint32 of bf16 (round-to-nearest-even).
__device__ __forceinline__ uint32_t pack2_bf16(float a, float b) {
    uint32_t ua = __builtin_bit_cast(uint32_t, a);
    uint32_t ub = __builtin_bit_cast(uint32_t, b);
    ua += 0x7fffu + ((ua >> 16) & 1u);
    ub += 0x7fffu + ((ub >> 16) & 1u);
    return (ua >> 16) | (ub & 0xffff0000u);
}

// One node, ONE dispatch (round-1 A/B showed each extra dispatch costs ~1.4us
// while kernel-side staging work is latency-hidden under the harness floor).
// Block = (expert r, token chunk); issues all 64 strided W loads into regs
// FIRST (VMEM queue fills), then self-compacts its chunk while they fly,
// then packs->LDS and runs 16-token x 128-e MFMA tiles.
//
// Fragment layouts (gfx950, mfma_f32_16x16x32_bf16):
//   A: lane holds A[m=lane&15][k=(lane>>4)*8+j], j=0..7
//   B: lane holds B[k=(lane>>4)*8+j][n=lane&15]
//   D: lane,reg -> row m=(lane>>4)*4+reg, col n=lane&15   (m89-verified)
__global__ __launch_bounds__(TPB) void ltf_kernel(
    const int* __restrict__ pos, const float* __restrict__ x,
    const float* __restrict__ W, const float* __restrict__ bias,
    float* __restrict__ y, int ntok, int c0)
{
    // Wf: 32 tiles (kt=0..3, n=0..7) x 64 lanes x 16 B = 32 KB, frag-order.
    __shared__ uint32_t Wf[8192];
    __shared__ int lst[CH0];   // capacity == max chunk size: cannot overflow
    __shared__ int cnt;

    const int tid  = threadIdx.x;
    const int lane = tid & 63;
    const int wv   = tid >> 6;
    const int bid  = blockIdx.x;

    int r, start, C;
    if (bid < 8 * c0) { r = bid / c0; start = (bid - r * c0) * CH0; C = CH0; }
    else              { r = 8; start = (bid - 8 * c0) * CH8; C = CH8; }

    const int end = (start + C < ntok) ? start + C : ntok;

    // --- Phase 0: issue ALL independent global loads up front.
    // (a) W[r] staging: 8 frag slots/thread x 8 strided floats -> 64 regs.
    const float* Wr = W + (size_t)r * D * D;
    float wreg[64];
    #pragma unroll
    for (int i = 0; i < 8; ++i) {
        int s = i * TPB + tid;
        int l = s & 63, T = s >> 6;
        int q = l >> 4, m = l & 15;
        int kt = T >> 3, n = T & 7;
        const float* src = Wr + (kt * 32 + q * 8) * D + n * 16 + m;
        #pragma unroll
        for (int j = 0; j < 8; ++j) wreg[i * 8 + j] = src[j * D];
    }
    // (b) positions for this chunk (2 iterations max: CH0/TPB).
    int pv[CH0 / TPB];
    #pragma unroll
    for (int it = 0; it < CH0 / TPB; ++it) {
        int t = start + it * TPB + tid;
        pv[it] = (t < end) ? pos[t] : 0;   // masked by (t<end) below
    }
    // (c) per-lane bias for its 8 e-columns (n*16 + mloc).
    const int q = lane >> 4, mloc = lane & 15;
    float bvn[8];
    #pragma unroll
    for (int n = 0; n < 8; ++n) bvn[n] = bias[(size_t)r * D + n * 16 + mloc];

    if (tid == 0) cnt = 0;
    __syncthreads();

    // --- Phase 1: self-compact (runs while W loads are still in flight).
    #pragma unroll
    for (int it = 0; it < CH0 / TPB; ++it) {
        int t = start + it * TPB + tid;
        int rp = pv[it] < (NEXP - 1) ? pv[it] : (NEXP - 1);
        bool m = (t < end) && (rp == r);
        unsigned long long mask = __ballot(m);
        int nm = __popcll(mask);
        int base = 0;
        if (lane == 0 && nm > 0) base = atomicAdd(&cnt, nm);
        base = __shfl(base, 0);
        if (m) lst[base + __popcll(mask & ((1ull << lane) - 1ull))] = t;
    }

    // --- Phase 2: pack W regs -> bf16 frag-order LDS image.
    #pragma unroll
    for (int i = 0; i < 8; ++i) {
        int s = i * TPB + tid;
        uint32_t u0 = pack2_bf16(wreg[i * 8 + 0], wreg[i * 8 + 1]);
        uint32_t u1 = pack2_bf16(wreg[i * 8 + 2], wreg[i * 8 + 3]);
        uint32_t u2 = pack2_bf16(wreg[i * 8 + 4], wreg[i * 8 + 5]);
        uint32_t u3 = pack2_bf16(wreg[i * 8 + 6], wreg[i * 8 + 7]);
        *reinterpret_cast<uint4*>(&Wf[s * 4]) = uint4{u0, u1, u2, u3};
    }
    __syncthreads();

    const int nc = cnt;

    const int rounds = (nc + 63) >> 6;
    for (int rd = 0; rd < rounds; ++rd) {
        const int b16 = rd * 64 + wv * 16;   // this wave's 16-token group
        if (b16 >= nc) continue;

        int ta = b16 + mloc; if (ta >= nc) ta = nc - 1;  // dup tail (harmless)
        const int tokA = lst[ta];
        const float4* xrow = reinterpret_cast<const float4*>(x + (size_t)tokA * D);

        f32x4_t acc[8];
        #pragma unroll
        for (int n = 0; n < 8; ++n) acc[n] = f32x4_t{0.f, 0.f, 0.f, 0.f};

        #pragma unroll
        for (int kt = 0; kt < 4; ++kt) {
            // A-frag: x[tokA][kt*32 + q*8 .. +7] -> bf16x8, built in regs.
            float4 va = xrow[kt * 8 + q * 2];
            float4 vb = xrow[kt * 8 + q * 2 + 1];
            FragA a;
            a.u[0] = pack2_bf16(va.x, va.y);
            a.u[1] = pack2_bf16(va.z, va.w);
            a.u[2] = pack2_bf16(vb.x, vb.y);
            a.u[3] = pack2_bf16(vb.z, vb.w);
            #pragma unroll
            for (int n = 0; n < 8; ++n) {
                bf16x8_t bf = *reinterpret_cast<const bf16x8_t*>(
                    &Wf[(kt * 8 + n) * 256 + lane * 4]);
                acc[n] = __builtin_amdgcn_mfma_f32_16x16x32_bf16(
                    a.v, bf, acc[n], 0, 0, 0);
            }
        }

        // Epilogue: lane (q,reg) holds token row m = q*4+reg, col n*16+mloc.
        #pragma unroll
        for (int reg = 0; reg < 4; ++reg) {
            int tloc = b16 + q * 4 + reg;
            if (tloc < nc) {
                int tok = lst[tloc];
                float* yr = y + (size_t)tok * D + mloc;
                #pragma unroll
                for (int n = 0; n < 8; ++n)
                    yr[n * 16] = acc[n][reg] + bvn[n];
            }
        }
    }
}

extern "C" void kernel_launch(void* const* d_in, const int* in_sizes, int n_in,
                              void* d_out, int out_size, void* d_ws, size_t ws_size,
                              hipStream_t stream) {
    const int* pos  = (const int*)d_in[0];
    const float* x  = (const float*)d_in[1];
    const float* W  = (const float*)d_in[2];
    const float* b  = (const float*)d_in[3];
    float* y = (float*)d_out;

    const int ntok = in_sizes[0];            // T*B = 8192
    const int c0 = (ntok + CH0 - 1) / CH0;   // chunks per expert 0..7
    const int c8 = (ntok + CH8 - 1) / CH8;   // fine chunks for expert 8
    ltf_kernel<<<8 * c0 + c8, TPB, 0, stream>>>(pos, x, W, b, y, ntok, c0);
}